// Round 1
// baseline (2287.006 us; speedup 1.0000x reference)
//
#include <hip/hip_runtime.h>
#include <hip/hip_bf16.h>

#define HH 4
#define NR 20000
#define DIN 257
#define DS 256
#define MF 64
#define NKC 32
#define GSZ 16

// ---------------------------------------------------------------------------
// value projection: vout[h][n][0]=sqrt(1+|s|^2), vout[h][n][1+c]=space
// GEMM: (32 rows)x(256 cols), K=257, LDS tiled, 4x8 microtile per thread.
// ---------------------------------------------------------------------------
__global__ __launch_bounds__(256) void value_kernel(
    const float* __restrict__ x, const float* __restrict__ W,
    const float* __restrict__ b, float* __restrict__ vout)
{
  __shared__ __align__(16) float XT[32][36];
  __shared__ __align__(16) float Wl[32][256];
  __shared__ float rs[32][33];
  const int t = threadIdx.x;
  const int h = blockIdx.y;
  const int n0 = blockIdx.x * 32;
  const int tx = t & 31, ty = t >> 5;
  float acc[4][8];
#pragma unroll
  for (int i = 0; i < 4; i++)
#pragma unroll
    for (int j = 0; j < 8; j++) acc[i][j] = 0.f;

  const float* Wh = W + (long)h * DIN * DS;
  for (int k0 = 0; k0 < DIN; k0 += 32) {
    const int bk = min(32, DIN - k0);
    {
      const int r = t >> 3, kb = (t & 7) * 4;
      const float* xr = x + (long)(n0 + r) * DIN + k0 + kb;
#pragma unroll
      for (int j = 0; j < 4; j++) XT[kb + j][r] = (kb + j < bk) ? xr[j] : 0.f;
    }
#pragma unroll
    for (int rep = 0; rep < 8; rep++) {
      const int i4 = rep * 256 + t;
      const int kk = i4 >> 6, c4 = (i4 & 63) * 4;
      float4 wv = make_float4(0.f, 0.f, 0.f, 0.f);
      if (kk < bk) wv = *(const float4*)(Wh + (long)(k0 + kk) * DS + c4);
      *(float4*)&Wl[kk][c4] = wv;
    }
    __syncthreads();
    if (bk == 32) {
#pragma unroll 4
      for (int kk = 0; kk < 32; kk++) {
        const float4 x4 = *(const float4*)&XT[kk][ty * 4];
        const float4 wa = *(const float4*)&Wl[kk][tx * 8];
        const float4 wb = *(const float4*)&Wl[kk][tx * 8 + 4];
        const float xr_[4] = {x4.x, x4.y, x4.z, x4.w};
        const float wv_[8] = {wa.x, wa.y, wa.z, wa.w, wb.x, wb.y, wb.z, wb.w};
#pragma unroll
        for (int i = 0; i < 4; i++)
#pragma unroll
          for (int j = 0; j < 8; j++) acc[i][j] = fmaf(xr_[i], wv_[j], acc[i][j]);
      }
    } else {
      for (int kk = 0; kk < bk; kk++) {
        const float4 x4 = *(const float4*)&XT[kk][ty * 4];
        const float4 wa = *(const float4*)&Wl[kk][tx * 8];
        const float4 wb = *(const float4*)&Wl[kk][tx * 8 + 4];
        const float xr_[4] = {x4.x, x4.y, x4.z, x4.w};
        const float wv_[8] = {wa.x, wa.y, wa.z, wa.w, wb.x, wb.y, wb.z, wb.w};
#pragma unroll
        for (int i = 0; i < 4; i++)
#pragma unroll
          for (int j = 0; j < 8; j++) acc[i][j] = fmaf(xr_[i], wv_[j], acc[i][j]);
      }
    }
    __syncthreads();
  }
  const int r0 = ty * 4;
  float bias[8];
  const float* bh = b + (long)h * DS + tx * 8;
#pragma unroll
  for (int j = 0; j < 8; j++) bias[j] = bh[j];
#pragma unroll
  for (int i = 0; i < 4; i++) {
    float s = 0.f;
#pragma unroll
    for (int j = 0; j < 8; j++) {
      acc[i][j] += bias[j];
      s = fmaf(acc[i][j], acc[i][j], s);
    }
    rs[r0 + i][tx] = s;
  }
  __syncthreads();
  if (t < 32) {
    float s = 0.f;
#pragma unroll
    for (int c = 0; c < 32; c++) s += rs[t][c];
    vout[((long)h * NR + n0 + t) * DIN] = sqrtf(1.f + s);
  }
#pragma unroll
  for (int i = 0; i < 4; i++) {
    float* vo = vout + ((long)h * NR + n0 + r0 + i) * DIN + 1 + tx * 8;
#pragma unroll
    for (int j = 0; j < 8; j++) vo[j] = acc[i][j];
  }
}

// ---------------------------------------------------------------------------
// query/key projection + random-feature softmax kernel.
// Phase1 = same GEMM; epilogue stores the space tile back into Wl (32x260,
// padded: phase2 reads Wl[r][d] with r*260+d -> conflict-free), then
// f[r][m] = exp(sqrt(2)*dot(space_r, proj[:,m])) * (0.125*exp(-|s|^2)+1e-8)
// ---------------------------------------------------------------------------
__global__ __launch_bounds__(256) void qk_kernel(
    const float* __restrict__ x, const float* __restrict__ W,
    const float* __restrict__ b, const float* __restrict__ proj,
    float* __restrict__ fout)
{
  __shared__ __align__(16) float XT[32][36];
  __shared__ __align__(16) float Wl[32][260];
  __shared__ float rs[32][33];
  __shared__ float frontl[32];
  const int t = threadIdx.x;
  const int h = blockIdx.y;
  const int n0 = blockIdx.x * 32;
  const int tx = t & 31, ty = t >> 5;
  float acc[4][8];
#pragma unroll
  for (int i = 0; i < 4; i++)
#pragma unroll
    for (int j = 0; j < 8; j++) acc[i][j] = 0.f;

  const float* Wh = W + (long)h * DIN * DS;
  for (int k0 = 0; k0 < DIN; k0 += 32) {
    const int bk = min(32, DIN - k0);
    {
      const int r = t >> 3, kb = (t & 7) * 4;
      const float* xr = x + (long)(n0 + r) * DIN + k0 + kb;
#pragma unroll
      for (int j = 0; j < 4; j++) XT[kb + j][r] = (kb + j < bk) ? xr[j] : 0.f;
    }
#pragma unroll
    for (int rep = 0; rep < 8; rep++) {
      const int i4 = rep * 256 + t;
      const int kk = i4 >> 6, c4 = (i4 & 63) * 4;
      float4 wv = make_float4(0.f, 0.f, 0.f, 0.f);
      if (kk < bk) wv = *(const float4*)(Wh + (long)(k0 + kk) * DS + c4);
      *(float4*)&Wl[kk][c4] = wv;
    }
    __syncthreads();
    if (bk == 32) {
#pragma unroll 4
      for (int kk = 0; kk < 32; kk++) {
        const float4 x4 = *(const float4*)&XT[kk][ty * 4];
        const float4 wa = *(const float4*)&Wl[kk][tx * 8];
        const float4 wb = *(const float4*)&Wl[kk][tx * 8 + 4];
        const float xr_[4] = {x4.x, x4.y, x4.z, x4.w};
        const float wv_[8] = {wa.x, wa.y, wa.z, wa.w, wb.x, wb.y, wb.z, wb.w};
#pragma unroll
        for (int i = 0; i < 4; i++)
#pragma unroll
          for (int j = 0; j < 8; j++) acc[i][j] = fmaf(xr_[i], wv_[j], acc[i][j]);
      }
    } else {
      for (int kk = 0; kk < bk; kk++) {
        const float4 x4 = *(const float4*)&XT[kk][ty * 4];
        const float4 wa = *(const float4*)&Wl[kk][tx * 8];
        const float4 wb = *(const float4*)&Wl[kk][tx * 8 + 4];
        const float xr_[4] = {x4.x, x4.y, x4.z, x4.w};
        const float wv_[8] = {wa.x, wa.y, wa.z, wa.w, wb.x, wb.y, wb.z, wb.w};
#pragma unroll
        for (int i = 0; i < 4; i++)
#pragma unroll
          for (int j = 0; j < 8; j++) acc[i][j] = fmaf(xr_[i], wv_[j], acc[i][j]);
      }
    }
    __syncthreads();
  }
  const int r0 = ty * 4;
  float bias[8];
  const float* bh = b + (long)h * DS + tx * 8;
#pragma unroll
  for (int j = 0; j < 8; j++) bias[j] = bh[j];
#pragma unroll
  for (int i = 0; i < 4; i++) {
    float s = 0.f;
#pragma unroll
    for (int j = 0; j < 8; j++) {
      const float vsp = acc[i][j] + bias[j];
      s = fmaf(vsp, vsp, s);
      Wl[r0 + i][tx * 8 + j] = vsp;  // space tile replaces W tile
    }
    rs[r0 + i][tx] = s;
  }
  __syncthreads();
  if (t < 32) {
    float s = 0.f;
#pragma unroll
    for (int c = 0; c < 32; c++) s += rs[t][c];
    frontl[t] = 0.125f * __expf(-s) + 1e-8f;  // exp((2-2t^2)/2)*m+eps, t^2=1+s
  }
  __syncthreads();
  // phase 2: thread -> row r, 8 contiguous features
  const int r = t >> 3, mg = (t & 7) * 8;
  float a8[8] = {0.f, 0.f, 0.f, 0.f, 0.f, 0.f, 0.f, 0.f};
  for (int d = 0; d < DS; d++) {
    const float sv = Wl[r][d];
    const float4 p0 = *(const float4*)(proj + (long)d * MF + mg);
    const float4 p1 = *(const float4*)(proj + (long)d * MF + mg + 4);
    a8[0] = fmaf(sv, p0.x, a8[0]); a8[1] = fmaf(sv, p0.y, a8[1]);
    a8[2] = fmaf(sv, p0.z, a8[2]); a8[3] = fmaf(sv, p0.w, a8[3]);
    a8[4] = fmaf(sv, p1.x, a8[4]); a8[5] = fmaf(sv, p1.y, a8[5]);
    a8[6] = fmaf(sv, p1.z, a8[6]); a8[7] = fmaf(sv, p1.w, a8[7]);
  }
  const float fr = frontl[r];
  const float SQ2 = 1.41421356237309515f;  // 1/sqrt(tau), tau=0.5
  float o[8];
#pragma unroll
  for (int j = 0; j < 8; j++) o[j] = __expf(SQ2 * a8[j]) * fr;
  float* fo = fout + ((long)h * NR + n0 + r) * MF + mg;
  *(float4*)fo = make_float4(o[0], o[1], o[2], o[3]);
  *(float4*)(fo + 4) = make_float4(o[4], o[5], o[6], o[7]);
}

// ---------------------------------------------------------------------------
// lastT[h][d][m] = sum_n v[h][n][d] * f[h][n][m]   (split-K partials)
// grid (dtile=5, kc=NKC, h=4); partial layout: ((kc*4+h)*257+d)*64+m
// ---------------------------------------------------------------------------
__global__ __launch_bounds__(256) void last_kernel(
    const float* __restrict__ v, const float* __restrict__ f,
    float* __restrict__ part)
{
  __shared__ __align__(16) float Al[16][68];
  __shared__ __align__(16) float Bl[16][64];
  const int t = threadIdx.x;
  const int dt = blockIdx.x, kc = blockIdx.y, h = blockIdx.z;
  const int d0 = dt * 64;
  const int nbeg = kc * 625, nend = nbeg + 625;  // 32*625 == 20000
  const int lr = t >> 4, lc4 = (t & 15) * 4;
  const int dm = (t & 15) * 4, mm = (t >> 4) * 4;
  float acc[4][4];
#pragma unroll
  for (int i = 0; i < 4; i++)
#pragma unroll
    for (int j = 0; j < 4; j++) acc[i][j] = 0.f;

  for (int n0 = nbeg; n0 < nend; n0 += 16) {
    const int nr = min(16, nend - n0);
    float av[4] = {0.f, 0.f, 0.f, 0.f};
    float4 bf = make_float4(0.f, 0.f, 0.f, 0.f);
    if (lr < nr) {
      const float* src = v + ((long)h * NR + n0 + lr) * DIN + d0 + lc4;
#pragma unroll
      for (int j = 0; j < 4; j++) av[j] = (d0 + lc4 + j < DIN) ? src[j] : 0.f;
      bf = *(const float4*)(f + ((long)h * NR + n0 + lr) * MF + lc4);
    }
    *(float4*)&Al[lr][lc4] = make_float4(av[0], av[1], av[2], av[3]);
    *(float4*)&Bl[lr][lc4] = bf;
    __syncthreads();
    const int kmax = nr;
#pragma unroll 4
    for (int kk = 0; kk < kmax; kk++) {
      const float4 a4 = *(const float4*)&Al[kk][dm];
      const float4 b4 = *(const float4*)&Bl[kk][mm];
      const float aa[4] = {a4.x, a4.y, a4.z, a4.w};
      const float bb[4] = {b4.x, b4.y, b4.z, b4.w};
#pragma unroll
      for (int i = 0; i < 4; i++)
#pragma unroll
        for (int j = 0; j < 4; j++) acc[i][j] = fmaf(aa[i], bb[j], acc[i][j]);
    }
    __syncthreads();
  }
#pragma unroll
  for (int i = 0; i < 4; i++) {
    const int d = d0 + dm + i;
    if (d < DIN)
      *(float4*)(part + (((long)(kc * HH + h) * DIN + d) * MF + mm)) =
          make_float4(acc[i][0], acc[i][1], acc[i][2], acc[i][3]);
  }
}

__global__ __launch_bounds__(256) void reduce_last(
    const float* __restrict__ part, float* __restrict__ lastT)
{
  const int o = blockIdx.x * 256 + threadIdx.x;  // < 257*256 = 65792
  float s = 0.f;
#pragma unroll 8
  for (int kc = 0; kc < NKC; kc++) s += part[(long)kc * 65792 + o];
  lastT[o] = s;
}

// ---------------------------------------------------------------------------
// fused: z = qp @ lastT, coeff normalize, mobius(v, z*coeff), mean over h,
// hyperbolic aggregate. 16 rows per block, 320 threads (d = t, t<257 active).
// ---------------------------------------------------------------------------
#define BATCH_REDUCE(DST)                                                   \
  do {                                                                      \
    for (int g_ = w; g_ < GSZ; g_ += 5) {                                   \
      float s_ = 0.f;                                                       \
      for (int j_ = 0; j_ < 5; j_++) s_ += red[g_ * 320 + l + 64 * j_];     \
      for (int off_ = 32; off_; off_ >>= 1) s_ += __shfl_down(s_, off_);    \
      if (l == 0) DST[g_] = s_;                                             \
    }                                                                       \
  } while (0)

__global__ __launch_bounds__(320) void fuse_kernel(
    const float* __restrict__ qp, const float* __restrict__ lastT,
    const float* __restrict__ v, float* __restrict__ out)
{
  __shared__ __align__(16) float qpl[HH * GSZ * MF];
  __shared__ float red[GSZ * 320];
  __shared__ float bcm[GSZ], bcA[GSZ], bcB[GSZ], bcC[GSZ];
  const int t = threadIdx.x;
  const int n0 = blockIdx.x * GSZ;
  const int w = t >> 6, l = t & 63;
  const bool act = (t < DIN);
  const int d = t;
  for (int h = 0; h < HH; h++)
    for (int idx = t; idx < GSZ * MF; idx += 320)
      qpl[h * GSZ * MF + idx] = qp[((long)h * NR + n0) * MF + idx];
  __syncthreads();
  float macc[GSZ];
#pragma unroll
  for (int g = 0; g < GSZ; g++) macc[g] = 0.f;
  const float sgn = (t == 0) ? -1.f : 1.f;  // Minkowski sign for d==0

  for (int h = 0; h < HH; h++) {
    float zb[GSZ];
#pragma unroll
    for (int g = 0; g < GSZ; g++) zb[g] = 0.f;
    if (act) {
      const float* lt = lastT + ((long)h * DIN + d) * MF;
      for (int mq = 0; mq < MF; mq += 4) {
        const float4 l4 = *(const float4*)(lt + mq);
#pragma unroll
        for (int g = 0; g < GSZ; g++) {
          const float4 q4 = *(const float4*)&qpl[(h * GSZ + g) * MF + mq];
          zb[g] = fmaf(q4.x, l4.x,
                  fmaf(q4.y, l4.y, fmaf(q4.z, l4.z, fmaf(q4.w, l4.w, zb[g]))));
        }
      }
    }
    // mnorm(z) per row
#pragma unroll
    for (int g = 0; g < GSZ; g++) red[g * 320 + t] = sgn * zb[g] * zb[g];
    __syncthreads();
    BATCH_REDUCE(bcm);
    __syncthreads();
    float av[GSZ];
#pragma unroll
    for (int g = 0; g < GSZ; g++) {
      const float cf = 1.f / sqrtf(fabsf(bcm[g] + 1e-7f));
      zb[g] *= cf;  // zb = b = _value
      av[g] = act ? v[((long)h * NR + n0 + g) * DIN + d] : 0.f;
    }
    // mobius sums: ab, a2, b2
#pragma unroll
    for (int g = 0; g < GSZ; g++) red[g * 320 + t] = av[g] * zb[g];
    __syncthreads();
    BATCH_REDUCE(bcA);
    __syncthreads();
#pragma unroll
    for (int g = 0; g < GSZ; g++) red[g * 320 + t] = av[g] * av[g];
    __syncthreads();
    BATCH_REDUCE(bcB);
    __syncthreads();
#pragma unroll
    for (int g = 0; g < GSZ; g++) red[g * 320 + t] = zb[g] * zb[g];
    __syncthreads();
    BATCH_REDUCE(bcC);
    __syncthreads();
#pragma unroll
    for (int g = 0; g < GSZ; g++) {
      const float ab = bcA[g], a2 = bcB[g], b2 = bcC[g];
      const float num = (1.f + 2.f * ab + b2) * av[g] + (1.f - a2) * zb[g];
      const float den = 1.f + 2.f * ab + a2 * b2;
      macc[g] = fmaf(num / (den + 1e-7f), 0.25f, macc[g]);  // mean over H=4
    }
    __syncthreads();
  }
  // final hyperbolic aggregate
#pragma unroll
  for (int g = 0; g < GSZ; g++) red[g * 320 + t] = sgn * macc[g] * macc[g];
  __syncthreads();
  BATCH_REDUCE(bcm);
  __syncthreads();
  if (act) {
#pragma unroll
    for (int g = 0; g < GSZ; g++)
      out[(long)(n0 + g) * DIN + d] = macc[g] / sqrtf(fabsf(bcm[g]) + 1e-7f);
  }
}

extern "C" void kernel_launch(void* const* d_in, const int* in_sizes, int n_in,
                              void* d_out, int out_size, void* d_ws, size_t ws_size,
                              hipStream_t stream) {
  const float* u    = (const float*)d_in[0];
  const float* ii   = (const float*)d_in[1];
  const float* Wk   = (const float*)d_in[2];
  const float* bk   = (const float*)d_in[3];
  const float* Wq   = (const float*)d_in[4];
  const float* bq   = (const float*)d_in[5];
  const float* Wv   = (const float*)d_in[6];
  const float* bv   = (const float*)d_in[7];
  const float* proj = (const float*)d_in[8];
  float* out = (float*)d_out;
  float* ws = (float*)d_ws;

  const long NV = (long)HH * NR * DIN;  // 20,560,000
  const long NF = (long)HH * NR * MF;   //  5,120,000
  float* v_u     = ws;
  float* v_i     = v_u + NV;
  float* qp_u    = v_i + NV;
  float* kp_u    = qp_u + NF;
  float* qp_i    = kp_u + NF;
  float* kp_i    = qp_i + NF;
  float* lastT_u = kp_i + NF;            // 65792 each
  float* lastT_i = lastT_u + 65792;
  float* part    = lastT_i + 65792;      // NKC * 65792
  // total ≈ 63.8M floats ≈ 244 MiB

  dim3 gp(NR / 32, HH);
  value_kernel<<<gp, 256, 0, stream>>>(u,  Wv, bv, v_u);
  value_kernel<<<gp, 256, 0, stream>>>(ii, Wv, bv, v_i);
  qk_kernel<<<gp, 256, 0, stream>>>(u,  Wq, bq, proj, qp_u);
  qk_kernel<<<gp, 256, 0, stream>>>(u,  Wk, bk, proj, kp_u);
  qk_kernel<<<gp, 256, 0, stream>>>(ii, Wq, bq, proj, qp_i);
  qk_kernel<<<gp, 256, 0, stream>>>(ii, Wk, bk, proj, kp_i);

  // u-side: kernelized(u_query, i_key, i_value) -> lastT_u from (v_i, kp_i)
  last_kernel<<<dim3(5, NKC, HH), 256, 0, stream>>>(v_i, kp_i, part);
  reduce_last<<<257, 256, 0, stream>>>(part, lastT_u);
  // i-side: kernelized(i_query, u_key, u_value) -> lastT_i from (v_u, kp_u)
  last_kernel<<<dim3(5, NKC, HH), 256, 0, stream>>>(v_u, kp_u, part);
  reduce_last<<<257, 256, 0, stream>>>(part, lastT_i);

  fuse_kernel<<<NR / GSZ, 320, 0, stream>>>(qp_u, lastT_u, v_u, out);
  fuse_kernel<<<NR / GSZ, 320, 0, stream>>>(qp_i, lastT_i, v_i, out + (long)NR * DIN);
}

// Round 2
// 1030.711 us; speedup vs baseline: 2.2189x; 2.2189x over previous
//
#include <hip/hip_runtime.h>
#include <hip/hip_bf16.h>

#define HH 4
#define NR 20000
#define DIN 257
#define DS 256
#define MF 64
#define KP 288   // padded K for bf16 staging (9 chunks of 32)
#define NKC 32
#define GSZ 16

typedef __bf16 bf16;
typedef bf16 bf16x8 __attribute__((ext_vector_type(8)));
typedef bf16 bf16x4 __attribute__((ext_vector_type(4)));
typedef float f32x4 __attribute__((ext_vector_type(4)));

__device__ __forceinline__ void load_lds16(const void* g, void* l) {
  __builtin_amdgcn_global_load_lds((const __attribute__((address_space(1))) void*)g,
                                   (__attribute__((address_space(3))) void*)l,
                                   16, 0, 0);
}

// ---------------------------------------------------------------------------
// conversion kernels (run once per call; tiny)
// ---------------------------------------------------------------------------
__global__ void cvt_x_kernel(const float* __restrict__ x, bf16* __restrict__ xb) {
  const int n = blockIdx.x, k = threadIdx.x;  // 288 threads
  xb[(long)n * KP + k] = (k < DIN) ? (bf16)x[(long)n * DIN + k] : (bf16)0.f;
}

__global__ void cvt_w_kernel(const float* __restrict__ Wq, const float* __restrict__ Wk,
                             const float* __restrict__ Wv, bf16* __restrict__ WbTq,
                             bf16* __restrict__ WbTk, bf16* __restrict__ WbTv) {
  const int which = blockIdx.y;
  const int h = blockIdx.x >> 8, n = blockIdx.x & 255, k = threadIdx.x;
  const float* W = which == 0 ? Wq : (which == 1 ? Wk : Wv);
  bf16* o = which == 0 ? WbTq : (which == 1 ? WbTk : WbTv);
  o[((long)h * 256 + n) * KP + k] =
      (k < DIN) ? (bf16)W[((long)h * DIN + k) * DS + n] : (bf16)0.f;
}

__global__ void cvt_p_kernel(const float* __restrict__ proj, bf16* __restrict__ projT) {
  const int nm = blockIdx.x, k = threadIdx.x;  // 64 x 256
  projT[nm * 256 + k] = (bf16)proj[(long)k * MF + nm];
}

// ---------------------------------------------------------------------------
// MFMA projection kernel. MODE 0: value (fp32 hyperboloid out, layout (h,n,257))
// MODE 1: qk (bf16 random-feature out, layout (h,n,64))
// Block: 256 thr = 4 waves; tile 64 rows x 256 cols; K chunks of 32 (KP=288).
// A_lds [64][40] padded (conflict-free frags); B_lds [quad][n][8] fragment-
// contiguous, filled by global_load_lds width=16.
// ---------------------------------------------------------------------------
template <int MODE>
__global__ __launch_bounds__(256) void proj_kernel(
    const bf16* __restrict__ xb, const bf16* __restrict__ WbT,
    const float* __restrict__ b, const bf16* __restrict__ projT,
    float* __restrict__ vout, bf16* __restrict__ fout)
{
  __shared__ __align__(16) unsigned char smem[35072];
  bf16* As = (bf16*)smem;              // [64][40]  (5120 B)
  bf16* Bs = (bf16*)(smem + 5120);     // [4][256][8] (16384 B)
  bf16* Ss = (bf16*)smem;              // phase2: [64][264] (33792 B, aliases A/B)
  float* rs = (float*)(smem + 33792);  // [64][4]
  float* fr = (float*)(smem + 34816);  // [64]

  const int t = threadIdx.x;
  const int h = blockIdx.y;
  const int n0 = blockIdx.x * 64;
  const int w = t >> 6, lane = t & 63;
  const int m16 = lane & 15, q = lane >> 4;

  f32x4 acc[4][4] = {};
  const bf16* wbh = WbT + (long)h * 256 * KP;

  for (int c = 0; c < 9; c++) {
    const int k0 = c * 32;
    {  // A stage: 64 rows x 32 k, padded stride 40
      const int row = t >> 2, ko = (t & 3) * 8;
      const int rv = min(n0 + row, NR - 1);
      bf16x8 av = *(const bf16x8*)(xb + (long)rv * KP + k0 + ko);
      *(bf16x8*)(As + row * 40 + ko) = av;
    }
    {  // B stage: wave w = k-quad w, all 256 n, direct-to-LDS
      const bf16* gb = wbh + k0 + w * 8;
      for (int s = 0; s < 4; s++) {
        const int n = s * 64 + lane;
        load_lds16(gb + (long)n * KP, Bs + w * 2048 + s * 512);
      }
    }
    __syncthreads();
    bf16x8 af[4], bfj[4];
#pragma unroll
    for (int i = 0; i < 4; i++)
      af[i] = *(const bf16x8*)(As + (i * 16 + m16) * 40 + q * 8);
#pragma unroll
    for (int j = 0; j < 4; j++)
      bfj[j] = *(const bf16x8*)(Bs + q * 2048 + (w * 64 + j * 16 + m16) * 8);
#pragma unroll
    for (int i = 0; i < 4; i++)
#pragma unroll
      for (int j = 0; j < 4; j++)
        acc[i][j] = __builtin_amdgcn_mfma_f32_16x16x32_bf16(af[i], bfj[j], acc[i][j], 0, 0, 0);
    __syncthreads();
  }

  // bias add (col = w*64 + j*16 + m16)
  float bias[4];
#pragma unroll
  for (int j = 0; j < 4; j++) bias[j] = b[h * DS + w * 64 + j * 16 + m16];
#pragma unroll
  for (int i = 0; i < 4; i++)
#pragma unroll
    for (int j = 0; j < 4; j++)
#pragma unroll
      for (int r = 0; r < 4; r++) acc[i][j][r] += bias[j];

  // per-row |s|^2: lane partial over its 4 cols, xor-reduce over the 16 m-lanes
#pragma unroll
  for (int i = 0; i < 4; i++)
#pragma unroll
    for (int r = 0; r < 4; r++) {
      float s = acc[i][0][r] * acc[i][0][r] + acc[i][1][r] * acc[i][1][r] +
                acc[i][2][r] * acc[i][2][r] + acc[i][3][r] * acc[i][3][r];
      for (int off = 1; off < 16; off <<= 1) s += __shfl_xor(s, off);
      if (m16 == 0) rs[(i * 16 + q * 4 + r) * 4 + w] = s;
    }
  __syncthreads();

  if (MODE == 0) {
    if (t < 64) {
      const float ss = rs[t * 4] + rs[t * 4 + 1] + rs[t * 4 + 2] + rs[t * 4 + 3];
      if (n0 + t < NR) vout[((long)h * NR + n0 + t) * DIN] = sqrtf(1.f + ss);
    }
#pragma unroll
    for (int i = 0; i < 4; i++) {
      const int row = i * 16 + q * 4;
#pragma unroll
      for (int r = 0; r < 4; r++) {
        const int rg = n0 + row + r;
        if (rg < NR) {
          float* vo = vout + ((long)h * NR + rg) * DIN + 1 + w * 64 + m16;
          vo[0] = acc[i][0][r]; vo[16] = acc[i][1][r];
          vo[32] = acc[i][2][r]; vo[48] = acc[i][3][r];
        }
      }
    }
  } else {
    if (t < 64) {
      const float ss = rs[t * 4] + rs[t * 4 + 1] + rs[t * 4 + 2] + rs[t * 4 + 3];
      fr[t] = 0.125f * __expf(-ss) + 1e-8f;  // exp(1 - t^2)*m + eps, t^2 = 1+|s|^2
    }
    // stash space tile bf16 into Ss (aliases A/B, safe: all GEMM reads done)
#pragma unroll
    for (int i = 0; i < 4; i++)
#pragma unroll
      for (int j = 0; j < 4; j++)
#pragma unroll
        for (int r = 0; r < 4; r++)
          Ss[(i * 16 + q * 4 + r) * 264 + w * 64 + j * 16 + m16] = (bf16)acc[i][j][r];
    __syncthreads();
    // feature GEMM: (64 x 256) @ projT^T -> 64 x 64; wave w = col-tile w
    f32x4 fc[4] = {};
    const bf16* pT = projT + (w * 16 + m16) * 256 + q * 8;
#pragma unroll
    for (int s = 0; s < 8; s++) {
      bf16x8 pb = *(const bf16x8*)(pT + s * 32);
#pragma unroll
      for (int i = 0; i < 4; i++) {
        bf16x8 sa = *(const bf16x8*)(Ss + (i * 16 + m16) * 264 + s * 32 + q * 8);
        fc[i] = __builtin_amdgcn_mfma_f32_16x16x32_bf16(sa, pb, fc[i], 0, 0, 0);
      }
    }
    const float SQ2 = 1.41421356237309515f;  // 1/sqrt(tau)
#pragma unroll
    for (int i = 0; i < 4; i++) {
      const int row = i * 16 + q * 4;
#pragma unroll
      for (int r = 0; r < 4; r++) {
        const int rg = n0 + row + r;
        if (rg < NR)
          fout[((long)h * NR + rg) * MF + w * 16 + m16] =
              (bf16)(__expf(SQ2 * fc[i][r]) * fr[row + r]);
      }
    }
  }
}

// ---------------------------------------------------------------------------
// lastT[h][d][m] = sum_n v[h][n][d] * f[h][n][m]   (split-K partials)
// ---------------------------------------------------------------------------
__global__ __launch_bounds__(256) void last_kernel(
    const float* __restrict__ v, const bf16* __restrict__ f,
    float* __restrict__ part)
{
  __shared__ __align__(16) float Al[16][68];
  __shared__ __align__(16) float Bl[16][64];
  const int t = threadIdx.x;
  const int dt = blockIdx.x, kc = blockIdx.y, h = blockIdx.z;
  const int d0 = dt * 64;
  const int nbeg = kc * 625, nend = nbeg + 625;
  const int lr = t >> 4, lc4 = (t & 15) * 4;
  const int dm = (t & 15) * 4, mm = (t >> 4) * 4;
  float acc[4][4];
#pragma unroll
  for (int i = 0; i < 4; i++)
#pragma unroll
    for (int j = 0; j < 4; j++) acc[i][j] = 0.f;

  for (int n0 = nbeg; n0 < nend; n0 += 16) {
    const int nr = min(16, nend - n0);
    float av[4] = {0.f, 0.f, 0.f, 0.f};
    float4 bf = make_float4(0.f, 0.f, 0.f, 0.f);
    if (lr < nr) {
      const float* src = v + ((long)h * NR + n0 + lr) * DIN + d0 + lc4;
#pragma unroll
      for (int j = 0; j < 4; j++) av[j] = (d0 + lc4 + j < DIN) ? src[j] : 0.f;
      bf16x4 b4 = *(const bf16x4*)(f + ((long)h * NR + n0 + lr) * MF + lc4);
      bf = make_float4((float)b4[0], (float)b4[1], (float)b4[2], (float)b4[3]);
    }
    *(float4*)&Al[lr][lc4] = make_float4(av[0], av[1], av[2], av[3]);
    *(float4*)&Bl[lr][lc4] = bf;
    __syncthreads();
#pragma unroll 4
    for (int kk = 0; kk < nr; kk++) {
      const float4 a4 = *(const float4*)&Al[kk][dm];
      const float4 b4 = *(const float4*)&Bl[kk][mm];
      const float aa[4] = {a4.x, a4.y, a4.z, a4.w};
      const float bb[4] = {b4.x, b4.y, b4.z, b4.w};
#pragma unroll
      for (int i = 0; i < 4; i++)
#pragma unroll
        for (int j = 0; j < 4; j++) acc[i][j] = fmaf(aa[i], bb[j], acc[i][j]);
    }
    __syncthreads();
  }
#pragma unroll
  for (int i = 0; i < 4; i++) {
    const int d = d0 + dm + i;
    if (d < DIN)
      *(float4*)(part + (((long)(kc * HH + h) * DIN + d) * MF + mm)) =
          make_float4(acc[i][0], acc[i][1], acc[i][2], acc[i][3]);
  }
}

__global__ __launch_bounds__(256) void reduce_last(
    const float* __restrict__ part, float* __restrict__ lastT)
{
  const int o = blockIdx.x * 256 + threadIdx.x;  // < 257*256
  float s = 0.f;
#pragma unroll 8
  for (int kc = 0; kc < NKC; kc++) s += part[(long)kc * 65792 + o];
  lastT[o] = s;
}

// ---------------------------------------------------------------------------
// fused epilogue (unchanged except bf16 qp)
// ---------------------------------------------------------------------------
#define BATCH_REDUCE(DST)                                                   \
  do {                                                                      \
    for (int g_ = w; g_ < GSZ; g_ += 5) {                                   \
      float s_ = 0.f;                                                       \
      for (int j_ = 0; j_ < 5; j_++) s_ += red[g_ * 320 + l + 64 * j_];     \
      for (int off_ = 32; off_; off_ >>= 1) s_ += __shfl_down(s_, off_);    \
      if (l == 0) DST[g_] = s_;                                             \
    }                                                                       \
  } while (0)

__global__ __launch_bounds__(320) void fuse_kernel(
    const bf16* __restrict__ qp, const float* __restrict__ lastT,
    const float* __restrict__ v, float* __restrict__ out)
{
  __shared__ __align__(16) float qpl[HH * GSZ * MF];
  __shared__ float red[GSZ * 320];
  __shared__ float bcm[GSZ], bcA[GSZ], bcB[GSZ], bcC[GSZ];
  const int t = threadIdx.x;
  const int n0 = blockIdx.x * GSZ;
  const int w = t >> 6, l = t & 63;
  const bool act = (t < DIN);
  const int d = t;
  for (int h = 0; h < HH; h++) {
    const bf16* qpb = qp + ((long)h * NR + n0) * MF;
    for (int idx = t; idx < GSZ * MF; idx += 320)
      qpl[h * GSZ * MF + idx] = (float)qpb[idx];
  }
  __syncthreads();
  float macc[GSZ];
#pragma unroll
  for (int g = 0; g < GSZ; g++) macc[g] = 0.f;
  const float sgn = (t == 0) ? -1.f : 1.f;

  for (int h = 0; h < HH; h++) {
    float zb[GSZ];
#pragma unroll
    for (int g = 0; g < GSZ; g++) zb[g] = 0.f;
    if (act) {
      const float* lt = lastT + ((long)h * DIN + d) * MF;
      for (int mq = 0; mq < MF; mq += 4) {
        const float4 l4 = *(const float4*)(lt + mq);
#pragma unroll
        for (int g = 0; g < GSZ; g++) {
          const float4 q4 = *(const float4*)&qpl[(h * GSZ + g) * MF + mq];
          zb[g] = fmaf(q4.x, l4.x,
                  fmaf(q4.y, l4.y, fmaf(q4.z, l4.z, fmaf(q4.w, l4.w, zb[g]))));
        }
      }
    }
#pragma unroll
    for (int g = 0; g < GSZ; g++) red[g * 320 + t] = sgn * zb[g] * zb[g];
    __syncthreads();
    BATCH_REDUCE(bcm);
    __syncthreads();
    float av[GSZ];
#pragma unroll
    for (int g = 0; g < GSZ; g++) {
      const float cf = 1.f / sqrtf(fabsf(bcm[g] + 1e-7f));
      zb[g] *= cf;
      av[g] = act ? v[((long)h * NR + n0 + g) * DIN + d] : 0.f;
    }
#pragma unroll
    for (int g = 0; g < GSZ; g++) red[g * 320 + t] = av[g] * zb[g];
    __syncthreads();
    BATCH_REDUCE(bcA);
    __syncthreads();
#pragma unroll
    for (int g = 0; g < GSZ; g++) red[g * 320 + t] = av[g] * av[g];
    __syncthreads();
    BATCH_REDUCE(bcB);
    __syncthreads();
#pragma unroll
    for (int g = 0; g < GSZ; g++) red[g * 320 + t] = zb[g] * zb[g];
    __syncthreads();
    BATCH_REDUCE(bcC);
    __syncthreads();
#pragma unroll
    for (int g = 0; g < GSZ; g++) {
      const float ab = bcA[g], a2 = bcB[g], b2 = bcC[g];
      const float num = (1.f + 2.f * ab + b2) * av[g] + (1.f - a2) * zb[g];
      const float den = 1.f + 2.f * ab + a2 * b2;
      macc[g] = fmaf(num / (den + 1e-7f), 0.25f, macc[g]);
    }
    __syncthreads();
  }
#pragma unroll
  for (int g = 0; g < GSZ; g++) red[g * 320 + t] = sgn * macc[g] * macc[g];
  __syncthreads();
  BATCH_REDUCE(bcm);
  __syncthreads();
  if (act) {
#pragma unroll
    for (int g = 0; g < GSZ; g++)
      out[(long)(n0 + g) * DIN + d] = macc[g] / sqrtf(fabsf(bcm[g]) + 1e-7f);
  }
}

extern "C" void kernel_launch(void* const* d_in, const int* in_sizes, int n_in,
                              void* d_out, int out_size, void* d_ws, size_t ws_size,
                              hipStream_t stream) {
  const float* u    = (const float*)d_in[0];
  const float* ii   = (const float*)d_in[1];
  const float* Wk   = (const float*)d_in[2];
  const float* bk   = (const float*)d_in[3];
  const float* Wq   = (const float*)d_in[4];
  const float* bq   = (const float*)d_in[5];
  const float* Wv   = (const float*)d_in[6];
  const float* bv   = (const float*)d_in[7];
  const float* proj = (const float*)d_in[8];
  float* out = (float*)d_out;

  const long NV = (long)HH * NR * DIN;  // fp32
  const long NF = (long)HH * NR * MF;   // bf16
  float* v_u = (float*)d_ws;
  float* v_i = v_u + NV;
  bf16* qp_u = (bf16*)(v_i + NV);
  bf16* kp_u = qp_u + NF;
  bf16* qp_i = kp_u + NF;
  bf16* kp_i = qp_i + NF;
  float* lastT_u = (float*)(kp_i + NF);
  float* lastT_i = lastT_u + 65792;
  // R region: bf16 staging, later reused as split-K partials (temporally disjoint)
  bf16* xb_u  = (bf16*)(lastT_i + 65792);
  bf16* xb_i  = xb_u + (long)NR * KP;
  bf16* WbTq  = xb_i + (long)NR * KP;
  bf16* WbTk  = WbTq + 4 * 256 * KP;
  bf16* WbTv  = WbTk + 4 * 256 * KP;
  bf16* projT = WbTv + 4 * 256 * KP;
  float* part = (float*)xb_u;  // aliases staging region (dead after projections)
  // total ws ≈ 231 MB (< the 255 MB proven in round 1)

  cvt_x_kernel<<<NR, KP, 0, stream>>>(u, xb_u);
  cvt_x_kernel<<<NR, KP, 0, stream>>>(ii, xb_i);
  cvt_w_kernel<<<dim3(1024, 3), KP, 0, stream>>>(Wq, Wk, Wv, WbTq, WbTk, WbTv);
  cvt_p_kernel<<<64, 256, 0, stream>>>(proj, projT);

  dim3 gp((NR + 63) / 64, HH);  // 313 x 4
  proj_kernel<0><<<gp, 256, 0, stream>>>(xb_u, WbTv, bv, nullptr, v_u, nullptr);
  proj_kernel<0><<<gp, 256, 0, stream>>>(xb_i, WbTv, bv, nullptr, v_i, nullptr);
  proj_kernel<1><<<gp, 256, 0, stream>>>(xb_u, WbTq, bq, projT, nullptr, qp_u);
  proj_kernel<1><<<gp, 256, 0, stream>>>(xb_u, WbTk, bk, projT, nullptr, kp_u);
  proj_kernel<1><<<gp, 256, 0, stream>>>(xb_i, WbTq, bq, projT, nullptr, qp_i);
  proj_kernel<1><<<gp, 256, 0, stream>>>(xb_i, WbTk, bk, projT, nullptr, kp_i);

  last_kernel<<<dim3(5, NKC, HH), 256, 0, stream>>>(v_i, kp_i, part);
  reduce_last<<<257, 256, 0, stream>>>(part, lastT_u);
  last_kernel<<<dim3(5, NKC, HH), 256, 0, stream>>>(v_u, kp_u, part);
  reduce_last<<<257, 256, 0, stream>>>(part, lastT_i);

  fuse_kernel<<<NR / GSZ, 320, 0, stream>>>(qp_u, lastT_u, v_u, out);
  fuse_kernel<<<NR / GSZ, 320, 0, stream>>>(qp_i, lastT_i, v_i, out + (long)NR * DIN);
}